// Round 8
// baseline (177.482 us; speedup 1.0000x reference)
//
#include <hip/hip_runtime.h>

// ConcordanceCC: B=256 rows, T=65536 cols.
//   K0: recover per-row prefix-length L via 3-level 64-ary ballot search.
//   K1: partial sums read ONLY y,p; invalid chunks skip loads; boundary chunk
//       predicated. R7 change: preload ALL 16 float4 loads per thread into
//       registers (64 data VGPRs), pinned with sched_barrier(0), and
//       __launch_bounds__(256,2) so the register allocator is ALLOWED to keep
//       them live (previous builds capped at 32-60 VGPR → ~3 loads in flight
//       → latency-bound at 2.3 TB/s regardless of occupancy or data source).
//   K2: finalize ccc in fp64.
// fp64 accumulation throughout (absmax=0.0 in all passing runs).

#define B_ROWS 256
#define T_COLS 65536
#define CHUNKS 8                      // chunks per row
#define CHUNK_ELEMS (T_COLS / CHUNKS) // 8192
#define THREADS 256
#define VEC_ITERS (CHUNK_ELEMS / (THREADS * 4)) // 8 float4 per stream per thread

// ws layout: int lens[256] @ byte 0 ; double partials[2048*5] @ byte 1024 (80 KiB)

__global__ void ccc_len_kernel(const int* __restrict__ mask, int* __restrict__ lens)
{
    const int t    = threadIdx.x;
    const int lane = t & 63;
    const int row  = blockIdx.x * (THREADS / 64) + (t >> 6);
    const int* __restrict__ m = mask + (long)row * T_COLS;

    unsigned long long b1 = __ballot(m[lane * 1024] != 0);
    const int c1 = __popcll(b1);
    int L;
    if (c1 == 0) {
        L = 0;
    } else {
        const int base2 = (c1 - 1) * 1024;                 // q*1024 < L <= q*1024+1024
        unsigned long long b2 = __ballot(m[base2 + lane * 16] != 0);
        const int base3 = base2 + (__popcll(b2) - 1) * 16; // base3 < L <= base3+16
        unsigned long long b3 = __ballot((lane < 16) ? (m[base3 + lane] != 0) : 0);
        L = base3 + __popcll(b3);
    }
    if (lane == 0) lens[row] = L;
}

__global__ __launch_bounds__(THREADS, 2) void ccc_partial_kernel(
    const float* __restrict__ ytrue,
    const float* __restrict__ ypred,
    const int*   __restrict__ lens,
    double*      __restrict__ part)
{
    const int blk   = blockIdx.x;
    const int row   = blk / CHUNKS;
    const int chunk = blk % CHUNKS;
    const int L     = lens[row];              // block-uniform
    const int cbase = chunk * CHUNK_ELEMS;

    const int t = threadIdx.x;
    double st = 0.0, sp = 0.0, stt = 0.0, spp = 0.0, stp = 0.0;

    if (L > cbase) {
        const long base = (long)row * T_COLS + cbase;
        const float4* __restrict__ yt4 = (const float4*)(ytrue + base);
        const float4* __restrict__ yp4 = (const float4*)(ypred + base);

        // ---- phase 1: issue ALL 16 loads (256 B/thread) ----
        float4 A[VEC_ITERS];
        float4 P[VEC_ITERS];
#pragma unroll
        for (int i = 0; i < VEC_ITERS; ++i) A[i] = yt4[t + i * THREADS];
#pragma unroll
        for (int i = 0; i < VEC_ITERS; ++i) P[i] = yp4[t + i * THREADS];
        __builtin_amdgcn_sched_barrier(0);

#define ACC(YV, PV)                                                       \
        {                                                                 \
            const double yd = (double)(YV), pd = (double)(PV);            \
            st += yd;                                                     \
            sp += pd;                                                     \
            stt = fma(yd, yd, stt);                                       \
            spp = fma(pd, pd, spp);                                       \
            stp = fma(yd, pd, stp);                                       \
        }

        // ---- phase 2: consume ----
        if (L >= cbase + CHUNK_ELEMS) {
#pragma unroll
            for (int i = 0; i < VEC_ITERS; ++i) {
                ACC(A[i].x, P[i].x) ACC(A[i].y, P[i].y)
                ACC(A[i].z, P[i].z) ACC(A[i].w, P[i].w)
            }
        } else {
            const int Lloc = L - cbase;            // in (0, CHUNK_ELEMS)
#pragma unroll
            for (int i = 0; i < VEC_ITERS; ++i) {
                const int c0 = (t + i * THREADS) * 4;
                ACC((c0 + 0 < Lloc) ? A[i].x : 0.0f, (c0 + 0 < Lloc) ? P[i].x : 0.0f)
                ACC((c0 + 1 < Lloc) ? A[i].y : 0.0f, (c0 + 1 < Lloc) ? P[i].y : 0.0f)
                ACC((c0 + 2 < Lloc) ? A[i].z : 0.0f, (c0 + 2 < Lloc) ? P[i].z : 0.0f)
                ACC((c0 + 3 < Lloc) ? A[i].w : 0.0f, (c0 + 3 < Lloc) ? P[i].w : 0.0f)
            }
        }
#undef ACC
    }
    // else: fully-invalid chunk — contribute zeros (ws is poisoned, must write)

    // wave shuffle reduction, then LDS across the 4 waves
    double vals[5] = { st, sp, stt, spp, stp };
#pragma unroll
    for (int k = 0; k < 5; ++k) {
#pragma unroll
        for (int off = 32; off > 0; off >>= 1) {
            vals[k] += __shfl_down(vals[k], off, 64);
        }
    }

    __shared__ double red[THREADS / 64][5];
    const int wave = t >> 6;
    const int lane = t & 63;
    if (lane == 0) {
#pragma unroll
        for (int k = 0; k < 5; ++k) red[wave][k] = vals[k];
    }
    __syncthreads();

    if (t < 5) {
        double s = 0.0;
#pragma unroll
        for (int w = 0; w < THREADS / 64; ++w) s += red[w][t];
        part[(long)blk * 5 + t] = s;
    }
}

__global__ __launch_bounds__(B_ROWS) void ccc_final_kernel(
    const double* __restrict__ part,
    const int*    __restrict__ lens,
    float*        __restrict__ out)
{
    const int r = threadIdx.x;  // one thread per row

    double st = 0.0, sp = 0.0, stt = 0.0, spp = 0.0, stp = 0.0;
    const double* p = part + (long)r * CHUNKS * 5;
#pragma unroll
    for (int c = 0; c < CHUNKS; ++c) {
        st  += p[c * 5 + 0];
        sp  += p[c * 5 + 1];
        stt += p[c * 5 + 2];
        spp += p[c * 5 + 3];
        stp += p[c * 5 + 4];
    }

    const double L      = (double)lens[r];
    const double mean_t = st / L;
    const double mean_p = sp / L;
    const double denom  = L - 1.0;
    const double var_t  = (stt - st * st / L) / denom;
    const double var_p  = (spp - sp * sp / L) / denom;
    const double cov    = (stp - st * sp / L) / denom;
    // NB: reference uses (mean_t - mean_p) * 2, not squared — reproduced.
    double ccc = 2.0 * cov / (var_t + var_p + 2.0 * (mean_t - mean_p));

    // block reduction of ccc over 256 rows
#pragma unroll
    for (int off = 32; off > 0; off >>= 1) {
        ccc += __shfl_down(ccc, off, 64);
    }
    __shared__ double red[B_ROWS / 64];
    const int wave = r >> 6;
    const int lane = r & 63;
    if (lane == 0) red[wave] = ccc;
    __syncthreads();

    if (r == 0) {
        double s = 0.0;
#pragma unroll
        for (int w = 0; w < B_ROWS / 64; ++w) s += red[w];
        out[0] = (float)(s / (double)B_ROWS);
    }
}

extern "C" void kernel_launch(void* const* d_in, const int* in_sizes, int n_in,
                              void* d_out, int out_size, void* d_ws, size_t ws_size,
                              hipStream_t stream) {
    const float* ytrue = (const float*)d_in[0];
    const float* ypred = (const float*)d_in[1];
    const int*   mask  = (const int*)d_in[2];
    float* out = (float*)d_out;

    int*    lens = (int*)d_ws;                         // 1 KiB
    double* part = (double*)((char*)d_ws + 1024);      // 2048*5*8 = 80 KiB

    ccc_len_kernel<<<B_ROWS / (THREADS / 64), THREADS, 0, stream>>>(mask, lens);
    ccc_partial_kernel<<<B_ROWS * CHUNKS, THREADS, 0, stream>>>(ytrue, ypred, lens, part);
    ccc_final_kernel<<<1, B_ROWS, 0, stream>>>(part, lens, out);
}

// Round 9
// 177.131 us; speedup vs baseline: 1.0020x; 1.0020x over previous
//
#include <hip/hip_runtime.h>

// ConcordanceCC: B=256 rows, T=65536 cols.
//   K0: recover per-row prefix-length L via 3-level 64-ary ballot search.
//   K1: per-(row,chunk) partial sums. R8 change: global_load_lds async staging
//       into double-buffered LDS (16 KiB), 8 steps x (4KB y + 4KB p). Bypasses
//       VGPR-return loads entirely (previous rounds: time invariant to
//       occupancy/preload/data-source at VGPR=32 -> compiler-capped in-flight
//       loads). Consume phase reads LDS float4 + fp64 accumulate (proven exact).
//   K2: finalize ccc in fp64.

#define B_ROWS 256
#define T_COLS 65536
#define CHUNKS 8                       // chunks per row
#define CHUNK_ELEMS (T_COLS / CHUNKS)  // 8192
#define THREADS 256
#define STEP 1024                      // elements per stage step (per stream)
#define NSTEP (CHUNK_ELEMS / STEP)     // 8

// ws layout: int lens[256] @ byte 0 ; double partials[2048*5] @ byte 1024 (80 KiB)

__device__ __forceinline__ void async_cp16(const float* g, float* l) {
    // 16B per lane: global per-lane src -> LDS (wave-uniform base + lane*16)
    __builtin_amdgcn_global_load_lds(
        (const __attribute__((address_space(1))) void*)g,
        (__attribute__((address_space(3))) void*)l, 16, 0, 0);
}

__global__ void ccc_len_kernel(const int* __restrict__ mask, int* __restrict__ lens)
{
    const int t    = threadIdx.x;
    const int lane = t & 63;
    const int row  = blockIdx.x * (THREADS / 64) + (t >> 6);
    const int* __restrict__ m = mask + (long)row * T_COLS;

    unsigned long long b1 = __ballot(m[lane * 1024] != 0);
    const int c1 = __popcll(b1);
    int L;
    if (c1 == 0) {
        L = 0;
    } else {
        const int base2 = (c1 - 1) * 1024;                 // q*1024 < L <= q*1024+1024
        unsigned long long b2 = __ballot(m[base2 + lane * 16] != 0);
        const int base3 = base2 + (__popcll(b2) - 1) * 16; // base3 < L <= base3+16
        unsigned long long b3 = __ballot((lane < 16) ? (m[base3 + lane] != 0) : 0);
        L = base3 + __popcll(b3);
    }
    if (lane == 0) lens[row] = L;
}

__global__ __launch_bounds__(THREADS) void ccc_partial_kernel(
    const float* __restrict__ ytrue,
    const float* __restrict__ ypred,
    const int*   __restrict__ lens,
    double*      __restrict__ part)
{
    __shared__ float ldsY[2][STEP];   // 2 x 4 KiB
    __shared__ float ldsP[2][STEP];   // 2 x 4 KiB

    const int blk   = blockIdx.x;
    const int row   = blk / CHUNKS;
    const int chunk = blk % CHUNKS;
    const int L     = lens[row];              // block-uniform
    const int cbase = chunk * CHUNK_ELEMS;

    const int t    = threadIdx.x;
    const int wave = t >> 6;
    const int lane = t & 63;

    double st = 0.0, sp = 0.0, stt = 0.0, spp = 0.0, stp = 0.0;

    if (L > cbase) {                          // block-uniform branch
        const long base = (long)row * T_COLS + cbase;
        const float* __restrict__ gy = ytrue + base;
        const float* __restrict__ gp = ypred + base;
        const bool full = (L >= cbase + CHUNK_ELEMS);
        const int  Lloc = L - cbase;

        // stage step s into buffer b: wave w stages 1KB of y and 1KB of p
#define STAGE(S, BUF)                                                     \
        {                                                                 \
            const int off = (S) * STEP + wave * 256 + lane * 4;           \
            async_cp16(gy + off, &ldsY[BUF][wave * 256]);                 \
            async_cp16(gp + off, &ldsP[BUF][wave * 256]);                 \
        }

#define ACC(YV, PV)                                                       \
        {                                                                 \
            const double yd = (double)(YV), pd = (double)(PV);            \
            st += yd;                                                     \
            sp += pd;                                                     \
            stt = fma(yd, yd, stt);                                       \
            spp = fma(pd, pd, spp);                                       \
            stp = fma(yd, pd, stp);                                       \
        }

        STAGE(0, 0)
#pragma unroll
        for (int s = 0; s < NSTEP; ++s) {
            const int buf = s & 1;
            if (s + 1 < NSTEP) STAGE(s + 1, (s + 1) & 1)
            __syncthreads();   // drains vmcnt -> stage(s) (and s+1) landed; waves synced

            const float4 a = *(const float4*)&ldsY[buf][t * 4];
            const float4 b = *(const float4*)&ldsP[buf][t * 4];
            if (full) {
                ACC(a.x, b.x) ACC(a.y, b.y) ACC(a.z, b.z) ACC(a.w, b.w)
            } else {
                const int c0 = s * STEP + t * 4;
                ACC((c0 + 0 < Lloc) ? a.x : 0.0f, (c0 + 0 < Lloc) ? b.x : 0.0f)
                ACC((c0 + 1 < Lloc) ? a.y : 0.0f, (c0 + 1 < Lloc) ? b.y : 0.0f)
                ACC((c0 + 2 < Lloc) ? a.z : 0.0f, (c0 + 2 < Lloc) ? b.z : 0.0f)
                ACC((c0 + 3 < Lloc) ? a.w : 0.0f, (c0 + 3 < Lloc) ? b.w : 0.0f)
            }
            __syncthreads();   // consume(s) done -> stage(s+2) may reuse buf
        }
#undef ACC
#undef STAGE
    }
    // else: fully-invalid chunk — contribute zeros (ws is poisoned, must write)

    // wave shuffle reduction, then LDS across the 4 waves
    double vals[5] = { st, sp, stt, spp, stp };
#pragma unroll
    for (int k = 0; k < 5; ++k) {
#pragma unroll
        for (int off = 32; off > 0; off >>= 1) {
            vals[k] += __shfl_down(vals[k], off, 64);
        }
    }

    __shared__ double red[THREADS / 64][5];
    if (lane == 0) {
#pragma unroll
        for (int k = 0; k < 5; ++k) red[wave][k] = vals[k];
    }
    __syncthreads();

    if (t < 5) {
        double s = 0.0;
#pragma unroll
        for (int w = 0; w < THREADS / 64; ++w) s += red[w][t];
        part[(long)blk * 5 + t] = s;
    }
}

__global__ __launch_bounds__(B_ROWS) void ccc_final_kernel(
    const double* __restrict__ part,
    const int*    __restrict__ lens,
    float*        __restrict__ out)
{
    const int r = threadIdx.x;  // one thread per row

    double st = 0.0, sp = 0.0, stt = 0.0, spp = 0.0, stp = 0.0;
    const double* p = part + (long)r * CHUNKS * 5;
#pragma unroll
    for (int c = 0; c < CHUNKS; ++c) {
        st  += p[c * 5 + 0];
        sp  += p[c * 5 + 1];
        stt += p[c * 5 + 2];
        spp += p[c * 5 + 3];
        stp += p[c * 5 + 4];
    }

    const double L      = (double)lens[r];
    const double mean_t = st / L;
    const double mean_p = sp / L;
    const double denom  = L - 1.0;
    const double var_t  = (stt - st * st / L) / denom;
    const double var_p  = (spp - sp * sp / L) / denom;
    const double cov    = (stp - st * sp / L) / denom;
    // NB: reference uses (mean_t - mean_p) * 2, not squared — reproduced.
    double ccc = 2.0 * cov / (var_t + var_p + 2.0 * (mean_t - mean_p));

    // block reduction of ccc over 256 rows
#pragma unroll
    for (int off = 32; off > 0; off >>= 1) {
        ccc += __shfl_down(ccc, off, 64);
    }
    __shared__ double red[B_ROWS / 64];
    const int wave = r >> 6;
    const int lane = r & 63;
    if (lane == 0) red[wave] = ccc;
    __syncthreads();

    if (r == 0) {
        double s = 0.0;
#pragma unroll
        for (int w = 0; w < B_ROWS / 64; ++w) s += red[w];
        out[0] = (float)(s / (double)B_ROWS);
    }
}

extern "C" void kernel_launch(void* const* d_in, const int* in_sizes, int n_in,
                              void* d_out, int out_size, void* d_ws, size_t ws_size,
                              hipStream_t stream) {
    const float* ytrue = (const float*)d_in[0];
    const float* ypred = (const float*)d_in[1];
    const int*   mask  = (const int*)d_in[2];
    float* out = (float*)d_out;

    int*    lens = (int*)d_ws;                         // 1 KiB
    double* part = (double*)((char*)d_ws + 1024);      // 2048*5*8 = 80 KiB

    ccc_len_kernel<<<B_ROWS / (THREADS / 64), THREADS, 0, stream>>>(mask, lens);
    ccc_partial_kernel<<<B_ROWS * CHUNKS, THREADS, 0, stream>>>(ytrue, ypred, lens, part);
    ccc_final_kernel<<<1, B_ROWS, 0, stream>>>(part, lens, out);
}